// Round 6
// baseline (3136.814 us; speedup 1.0000x reference)
//
#include <hip/hip_runtime.h>
#include <stdint.h>

typedef __attribute__((ext_vector_type(8))) short shortx8;
typedef __attribute__((ext_vector_type(4))) float floatx4;

#define NR 16384      // nodes (M and K of the big GEMM)
#define DD 256        // feature dim
#define NSPLIT 2      // split-K factor
#define KCH (NR / NSPLIT)   // 8192
#define BK 32         // K per iteration
#define NIT (KCH / BK)      // 256
#define SA 72         // k_lin LDS stride

// s_waitcnt simm16: vmcnt[3:0]=simm[3:0], expcnt=simm[6:4], lgkmcnt=simm[11:8], vmcnt[5:4]=simm[15:14]
#define WAIT_VM4 0x0F74   // vmcnt(4), lgkm/exp unconstrained
#define WAIT_VM0 0x0F70   // vmcnt(0), lgkm/exp unconstrained

__device__ __forceinline__ unsigned short f2bf(float f) {
    union { float f; uint32_t u; } v; v.f = f;
    uint32_t u = v.u;
    return (unsigned short)((u + 0x7FFFu + ((u >> 16) & 1u)) >> 16);
}

// ---------------------------------------------------------------------------
// Kernel 0: x [16384][256] f32  ->  xT [256][16384] bf16   (transpose+convert)
// ---------------------------------------------------------------------------
__global__ __launch_bounds__(256) void k_xpose(const float* __restrict__ x,
                                               unsigned short* __restrict__ xT) {
    __shared__ unsigned short t[64][72];
    const int kb = blockIdx.x * 64;
    const int nb = blockIdx.y * 64;
    const int tid = threadIdx.x;
    const int lr = tid >> 4;
    const int lc = (tid & 15) * 4;
#pragma unroll
    for (int i = 0; i < 4; ++i) {
        const int k = kb + lr + 16 * i;
        const float4 v = *(const float4*)(x + (size_t)k * DD + nb + lc);
        t[lc + 0][lr + 16 * i] = f2bf(v.x);
        t[lc + 1][lr + 16 * i] = f2bf(v.y);
        t[lc + 2][lr + 16 * i] = f2bf(v.z);
        t[lc + 3][lr + 16 * i] = f2bf(v.w);
    }
    __syncthreads();
#pragma unroll
    for (int i = 0; i < 4; ++i) {
        const int nl = lr + 16 * i;
        ushort4 o;
        o.x = t[nl][lc + 0]; o.y = t[nl][lc + 1];
        o.z = t[nl][lc + 2]; o.w = t[nl][lc + 3];
        *(ushort4*)(xT + (size_t)(nb + nl) * NR + kb + lc) = o;
    }
}

// ---------------------------------------------------------------------------
// Kernel 1: agg partials = adj @ x (+ fused deg row-sums)
// BARRIER-FREE main loop. Per wave: A-fragments loaded directly to registers
// (double-buffered, issued 1 iter ahead; 4-way wave-redundant, L2-merged);
// B rows are wave-private in LDS (wave w stages and reads rows w*64..w*64+63)
// via global_load_lds into 3 rotating buffers (stage it+2, read it).
// Pacing: one s_waitcnt vmcnt(4) per iteration (pops B(it)+A(it), leaves
// B(it+1) in flight). Waves free-run; HBM queue never drains.
// ---------------------------------------------------------------------------
__global__ __launch_bounds__(256, 2) void k_agg(const int* __restrict__ adj,
                                                const unsigned short* __restrict__ xT,
                                                float* __restrict__ aggP,
                                                float* __restrict__ degP) {
    __shared__ __align__(16) unsigned short Bs[3][256 * 32];   // 3 x 16 KB
    __shared__ int degs[64];

    const int tid  = threadIdx.x;
    const int wave = tid >> 6;
    const int lane = tid & 63;
    const int q    = lane >> 4;       // quad 0..3
    const int ln   = lane & 15;
    const int m0   = blockIdx.x * 64;
    const int kb0  = blockIdx.y * KCH;

    if (tid < 64) degs[tid] = 0;
    __syncthreads();   // degs init visible before epilogue atomics

    // ---- A: direct per-lane pointers (row m0+mt*16+ln, cols q*8..q*8+7) ----
    const int* pA[4];
#pragma unroll
    for (int mt = 0; mt < 4; ++mt)
        pA[mt] = adj + (size_t)(m0 + mt * 16 + ln) * NR + kb0 + q * 8;

    // ---- B: wave-private staging (wave w covers xT rows w*64..w*64+63) ----
    const unsigned short* srcB[4];
#pragma unroll
    for (int j = 0; j < 4; ++j) {
        const int L = (wave * 4 + j) * 64 + lane;   // chunk id
        const int n = L >> 2;                        // xT row
        const int pb = L & 3;                        // 16B part in row
        srcB[j] = xT + (size_t)n * NR + kb0 + pb * 8;
    }

    floatx4 acc[4][4] = {};
    int dacc[4] = {0, 0, 0, 0};
    int4 ar[2][4][2];   // [phase][mt][c0/c1]

    // ---- prologue (issue order matters for the vmcnt FIFO) ----
    // B(0) x4
#pragma unroll
    for (int j = 0; j < 4; ++j) {
        __builtin_amdgcn_global_load_lds(
            (const __attribute__((address_space(1))) void*)srcB[j],
            (__attribute__((address_space(3))) void*)(Bs[0] + (wave * 4 + j) * 512),
            16, 0, 0);
        srcB[j] += BK;
    }
    // A(0) x8
#pragma unroll
    for (int mt = 0; mt < 4; ++mt) {
        ar[0][mt][0] = *(const int4*)(pA[mt]);
        ar[0][mt][1] = *(const int4*)(pA[mt] + 4);
        pA[mt] += BK;
    }
    // B(1) x4
#pragma unroll
    for (int j = 0; j < 4; ++j) {
        __builtin_amdgcn_global_load_lds(
            (const __attribute__((address_space(1))) void*)srcB[j],
            (__attribute__((address_space(3))) void*)(Bs[1] + (wave * 4 + j) * 512),
            16, 0, 0);
        srcB[j] += BK;
    }

    int cb = 0;   // consume buffer (it % 3)
    int sb = 2;   // stage buffer ((it+2) % 3)
    for (int it = 0; it < NIT; ++it) {
        const int cur = it & 1;
        // ---- pace: B(it) landed in LDS, A(it) regs landed; B(it+1) stays out
        if (it + 1 < NIT) __builtin_amdgcn_s_waitcnt(WAIT_VM4);
        else              __builtin_amdgcn_s_waitcnt(WAIT_VM0);

        // ---- convert A(it) regs -> bf16 frags ----
        shortx8 af[4], bf[4];
#pragma unroll
        for (int mt = 0; mt < 4; ++mt) {
            const int4 c0 = ar[cur][mt][0];
            const int4 c1 = ar[cur][mt][1];
            union { shortx8 v; uint32_t u[4]; } A;
            A.u[0] = (c0.x ? 0x3F80u : 0u) | (c0.y ? 0x3F800000u : 0u);
            A.u[1] = (c0.z ? 0x3F80u : 0u) | (c0.w ? 0x3F800000u : 0u);
            A.u[2] = (c1.x ? 0x3F80u : 0u) | (c1.y ? 0x3F800000u : 0u);
            A.u[3] = (c1.z ? 0x3F80u : 0u) | (c1.w ? 0x3F800000u : 0u);
            af[mt] = A.v;
            if (wave == 0)
                dacc[mt] += c0.x + c0.y + c0.z + c0.w + c1.x + c1.y + c1.z + c1.w;
        }
        // ---- B frags from own wave's private LDS rows ----
#pragma unroll
        for (int nt = 0; nt < 4; ++nt)
            bf[nt] = *(const shortx8*)&Bs[cb][(wave * 64 + nt * 16 + ln) * 32 + q * 8];
        // ---- 16 MFMA ----
#pragma unroll
        for (int mt = 0; mt < 4; ++mt)
#pragma unroll
            for (int nt = 0; nt < 4; ++nt)
                acc[mt][nt] = __builtin_amdgcn_mfma_f32_16x16x32_bf16(
                    af[mt], bf[nt], acc[mt][nt], 0, 0, 0);

        // ---- bottom: issue A(it+1) regs, then B(it+2) LDS-DMA ----
        if (it + 1 < NIT) {
#pragma unroll
            for (int mt = 0; mt < 4; ++mt) {
                ar[cur ^ 1][mt][0] = *(const int4*)(pA[mt]);
                ar[cur ^ 1][mt][1] = *(const int4*)(pA[mt] + 4);
                pA[mt] += BK;
            }
        }
        if (it + 2 < NIT) {
#pragma unroll
            for (int j = 0; j < 4; ++j) {
                __builtin_amdgcn_global_load_lds(
                    (const __attribute__((address_space(1))) void*)srcB[j],
                    (__attribute__((address_space(3))) void*)(Bs[sb] + (wave * 4 + j) * 512),
                    16, 0, 0);
                srcB[j] += BK;
            }
        }
        cb = (cb == 2) ? 0 : cb + 1;
        sb = (sb == 2) ? 0 : sb + 1;
    }

    // ---- deg reduce + write ----
    if (wave == 0) {
#pragma unroll
        for (int mt = 0; mt < 4; ++mt)
            atomicAdd(&degs[mt * 16 + ln], dacc[mt]);
    }
    __syncthreads();
    if (tid < 64) degP[(size_t)blockIdx.y * NR + m0 + tid] = (float)degs[tid];

    // ---- acc writeback (C/D layout: col=ln, row=q*4+r) ----
    float* const outb = aggP + (size_t)blockIdx.y * NR * DD;
#pragma unroll
    for (int mt = 0; mt < 4; ++mt)
#pragma unroll
        for (int nt = 0; nt < 4; ++nt)
#pragma unroll
            for (int r = 0; r < 4; ++r) {
                const int row = m0 + mt * 16 + q * 4 + r;
                const int col = wave * 64 + nt * 16 + ln;
                outb[(size_t)row * DD + col] = acc[mt][nt][r];
            }
}

// ---------------------------------------------------------------------------
// Kernel 2: out = ((p0+p1)/deg) @ W^T + b    M=16384, N=256, K=256
// ---------------------------------------------------------------------------
__global__ __launch_bounds__(256, 2) void k_lin(const float* __restrict__ aggP,
                                                const float* __restrict__ degP,
                                                const float* __restrict__ W,
                                                const float* __restrict__ bias,
                                                float* __restrict__ out) {
    __shared__ __align__(16) unsigned short As[64 * SA];
    __shared__ __align__(16) unsigned short Bs[256 * SA];
    __shared__ float rdeg[64];
    __shared__ float bsh[256];

    const int tid  = threadIdx.x;
    const int wave = tid >> 6;
    const int lane = tid & 63;
    const int q    = lane >> 4;
    const int ln   = lane & 15;
    const int m0   = blockIdx.x * 64;

    if (tid < 64) {
        float d = 0.f;
#pragma unroll
        for (int s = 0; s < NSPLIT; ++s) d += degP[(size_t)s * NR + m0 + tid];
        rdeg[tid] = 1.0f / d;
    }
    bsh[tid] = bias[tid];

    const int arow = tid >> 4;
    const int acol = (tid & 15) * 4;

    floatx4 acc[4][4] = {};

    for (int it = 0; it < 4; ++it) {
        const int kb = it * 64;
        __syncthreads();

#pragma unroll
        for (int i = 0; i < 4; ++i) {
            const int r = arow + 16 * i;
            const size_t g = (size_t)(m0 + r) * DD + kb + acol;
            float4 p = *(const float4*)(aggP + g);
#pragma unroll
            for (int s = 1; s < NSPLIT; ++s) {
                const float4 ps = *(const float4*)(aggP + (size_t)s * NR * DD + g);
                p.x += ps.x; p.y += ps.y; p.z += ps.z; p.w += ps.w;
            }
            const float sc = rdeg[r];
            ushort4 o;
            o.x = f2bf(p.x * sc);
            o.y = f2bf(p.y * sc);
            o.z = f2bf(p.z * sc);
            o.w = f2bf(p.w * sc);
            *(ushort4*)&As[r * SA + acol] = o;
        }
#pragma unroll
        for (int i = 0; i < 16; ++i) {
            const int r = arow + 16 * i;
            const float4 w4 = *(const float4*)(W + (size_t)r * DD + kb + acol);
            ushort4 o;
            o.x = f2bf(w4.x); o.y = f2bf(w4.y);
            o.z = f2bf(w4.z); o.w = f2bf(w4.w);
            *(ushort4*)&Bs[r * SA + acol] = o;
        }
        __syncthreads();

#pragma unroll
        for (int ks = 0; ks < 2; ++ks) {
            const int kk = ks * 32 + q * 8;
            shortx8 af[4], bf[4];
#pragma unroll
            for (int mt = 0; mt < 4; ++mt)
                af[mt] = *(const shortx8*)&As[(mt * 16 + ln) * SA + kk];
#pragma unroll
            for (int nt = 0; nt < 4; ++nt)
                bf[nt] = *(const shortx8*)&Bs[(wave * 64 + nt * 16 + ln) * SA + kk];
#pragma unroll
            for (int mt = 0; mt < 4; ++mt)
#pragma unroll
                for (int nt = 0; nt < 4; ++nt)
                    acc[mt][nt] = __builtin_amdgcn_mfma_f32_16x16x32_bf16(
                        af[mt], bf[nt], acc[mt][nt], 0, 0, 0);
        }
    }

#pragma unroll
    for (int mt = 0; mt < 4; ++mt)
#pragma unroll
        for (int nt = 0; nt < 4; ++nt)
#pragma unroll
            for (int r = 0; r < 4; ++r) {
                const int row = m0 + mt * 16 + q * 4 + r;
                const int col = wave * 64 + nt * 16 + ln;
                out[(size_t)row * DD + col] = acc[mt][nt][r] + bsh[col];
            }
}

// ---------------------------------------------------------------------------
extern "C" void kernel_launch(void* const* d_in, const int* in_sizes, int n_in,
                              void* d_out, int out_size, void* d_ws, size_t ws_size,
                              hipStream_t stream) {
    const float* x    = (const float*)d_in[0];
    const int*   adj  = (const int*)d_in[1];
    const float* W    = (const float*)d_in[2];
    const float* bias = (const float*)d_in[3];
    float* out = (float*)d_out;

    // ws layout: xT bf16 8 MB | aggP fp32 NSPLIT x 16 MB | degP fp32 NSPLIT x 64 KB
    unsigned short* xT  = (unsigned short*)d_ws;
    float* aggP = (float*)((char*)d_ws + (size_t)8 * 1024 * 1024);
    float* degP = (float*)((char*)d_ws + (size_t)(8 + 16 * NSPLIT) * 1024 * 1024);

    k_xpose<<<dim3(NR / 64, DD / 64), 256, 0, stream>>>(x, xT);
    k_agg<<<dim3(NR / 64, NSPLIT), 256, 0, stream>>>(adj, xT, aggP, degP);
    k_lin<<<dim3(NR / 64), 256, 0, stream>>>(aggP, degP, W, bias, out);
}

// Round 7
// 1845.999 us; speedup vs baseline: 1.6993x; 1.6993x over previous
//
#include <hip/hip_runtime.h>
#include <stdint.h>

typedef __attribute__((ext_vector_type(8))) short shortx8;
typedef __attribute__((ext_vector_type(4))) float floatx4;

#define NR 16384      // nodes (M and K of the big GEMM)
#define DD 256        // feature dim
#define NSPLIT 2      // split-K factor
#define KCH (NR / NSPLIT)   // 8192
#define BK 32         // K per iteration
#define NIT (KCH / BK)      // 256
#define SA 72         // k_lin LDS stride

// s_waitcnt simm16: vmcnt[3:0]=simm[3:0], expcnt=simm[6:4], lgkmcnt=simm[11:8], vmcnt[5:4]=simm[15:14]
#define WAIT_VM12 0x0F7C   // vmcnt(12)
#define WAIT_VM0  0x0F70   // vmcnt(0)

__device__ __forceinline__ unsigned short f2bf(float f) {
    union { float f; uint32_t u; } v; v.f = f;
    uint32_t u = v.u;
    return (unsigned short)((u + 0x7FFFu + ((u >> 16) & 1u)) >> 16);
}

// ---------------------------------------------------------------------------
// Kernel 0: x [16384][256] f32  ->  xT [256][16384] bf16   (transpose+convert)
// ---------------------------------------------------------------------------
__global__ __launch_bounds__(256) void k_xpose(const float* __restrict__ x,
                                               unsigned short* __restrict__ xT) {
    __shared__ unsigned short t[64][72];
    const int kb = blockIdx.x * 64;
    const int nb = blockIdx.y * 64;
    const int tid = threadIdx.x;
    const int lr = tid >> 4;
    const int lc = (tid & 15) * 4;
#pragma unroll
    for (int i = 0; i < 4; ++i) {
        const int k = kb + lr + 16 * i;
        const float4 v = *(const float4*)(x + (size_t)k * DD + nb + lc);
        t[lc + 0][lr + 16 * i] = f2bf(v.x);
        t[lc + 1][lr + 16 * i] = f2bf(v.y);
        t[lc + 2][lr + 16 * i] = f2bf(v.z);
        t[lc + 3][lr + 16 * i] = f2bf(v.w);
    }
    __syncthreads();
#pragma unroll
    for (int i = 0; i < 4; ++i) {
        const int nl = lr + 16 * i;
        ushort4 o;
        o.x = t[nl][lc + 0]; o.y = t[nl][lc + 1];
        o.z = t[nl][lc + 2]; o.w = t[nl][lc + 3];
        *(ushort4*)(xT + (size_t)(nb + nl) * NR + kb + lc) = o;
    }
}

// ---------------------------------------------------------------------------
// Kernel 1: agg partials = adj @ x (+ fused deg row-sums)
// Fully register-resident, BARRIER-FREE main loop, no LDS in the loop.
//  - B frags: direct global dwordx4 per lane == exact MFMA B-fragment bytes
//    (wave-exclusive rows, L2/L3-served re-reads). No LDS, no VALU.
//  - A frags: direct global int4 x2 per mt (4x wave-redundant, L2-merged),
//    converted 0/1 -> bf16 in regs.
//  - Two named phase buffers (ar0/br0, ar1/br1), manually 2-phased loop ->
//    all constant indices -> no scratch spill (R6's failure mode).
//  - Pacing: body(it) top waits vmcnt(12) (drains it's 12 loads, issued two
//    bodies earlier; leaves it+1's 12 in flight), bottom issues it+2's.
// ---------------------------------------------------------------------------
__global__ __launch_bounds__(256, 2) void k_agg(const int* __restrict__ adj,
                                                const unsigned short* __restrict__ xT,
                                                float* __restrict__ aggP,
                                                float* __restrict__ degP) {
    __shared__ int degs[64];

    const int tid  = threadIdx.x;
    const int wave = tid >> 6;
    const int lane = tid & 63;
    const int q    = lane >> 4;       // quad 0..3
    const int ln   = lane & 15;
    const int m0   = blockIdx.x * 64;
    const int kb0  = blockIdx.y * KCH;

    if (tid < 64) degs[tid] = 0;
    __syncthreads();

    // A pointers: row m0+mt*16+ln, k-cols q*8..q*8+7 (two int4 each)
    const int* pA[4];
#pragma unroll
    for (int mt = 0; mt < 4; ++mt)
        pA[mt] = adj + (size_t)(m0 + mt * 16 + ln) * NR + kb0 + q * 8;

    // B pointers: xT row wave*64+nt*16+ln, k-cols q*8..q*8+7 (one 16B load)
    const unsigned short* pB[4];
#pragma unroll
    for (int nt = 0; nt < 4; ++nt)
        pB[nt] = xT + (size_t)(wave * 64 + nt * 16 + ln) * NR + kb0 + q * 8;

    floatx4 acc[4][4] = {};
    int dacc[4] = {0, 0, 0, 0};

    int4 ar0[4][2], ar1[4][2];   // raw adj ints, phase 0/1
    int4 br0[4],    br1[4];      // raw bf16x8 B-frags, phase 0/1

#define AGG_ISSUE(arX, brX)                                                   \
    {                                                                         \
        _Pragma("unroll")                                                     \
        for (int mt = 0; mt < 4; ++mt) {                                      \
            arX[mt][0] = *(const int4*)(pA[mt]);                              \
            arX[mt][1] = *(const int4*)(pA[mt] + 4);                          \
            pA[mt] += BK;                                                     \
        }                                                                     \
        _Pragma("unroll")                                                     \
        for (int nt = 0; nt < 4; ++nt) {                                      \
            brX[nt] = *(const int4*)(pB[nt]);                                 \
            pB[nt] += BK;                                                     \
        }                                                                     \
    }

#define AGG_CONSUME(arX, brX)                                                 \
    {                                                                         \
        shortx8 bf[4];                                                        \
        _Pragma("unroll")                                                     \
        for (int nt = 0; nt < 4; ++nt) {                                      \
            union { int4 i; shortx8 s; } cvt; cvt.i = brX[nt];                \
            bf[nt] = cvt.s;                                                   \
        }                                                                     \
        _Pragma("unroll")                                                     \
        for (int mt = 0; mt < 4; ++mt) {                                      \
            const int4 c0 = arX[mt][0];                                       \
            const int4 c1 = arX[mt][1];                                       \
            union { shortx8 v; uint32_t u[4]; } A;                            \
            A.u[0] = (c0.x ? 0x3F80u : 0u) | (c0.y ? 0x3F800000u : 0u);       \
            A.u[1] = (c0.z ? 0x3F80u : 0u) | (c0.w ? 0x3F800000u : 0u);       \
            A.u[2] = (c1.x ? 0x3F80u : 0u) | (c1.y ? 0x3F800000u : 0u);       \
            A.u[3] = (c1.z ? 0x3F80u : 0u) | (c1.w ? 0x3F800000u : 0u);       \
            if (wave == 0)                                                    \
                dacc[mt] += c0.x + c0.y + c0.z + c0.w +                       \
                            c1.x + c1.y + c1.z + c1.w;                        \
            _Pragma("unroll")                                                 \
            for (int nt = 0; nt < 4; ++nt)                                    \
                acc[mt][nt] = __builtin_amdgcn_mfma_f32_16x16x32_bf16(        \
                    A.v, bf[nt], acc[mt][nt], 0, 0, 0);                       \
        }                                                                     \
    }

    // ---- prologue: issue it=0 (phase0) and it=1 (phase1): 24 loads out ----
    AGG_ISSUE(ar0, br0);
    AGG_ISSUE(ar1, br1);

    // ---- main loop: iters 0..NIT-3, two phases per trip, no barriers ----
    for (int it = 0; it < NIT - 2; it += 2) {
        __builtin_amdgcn_s_waitcnt(WAIT_VM12);   // drain it's loads
        AGG_CONSUME(ar0, br0);
        AGG_ISSUE(ar0, br0);                      // loads for it+2
        __builtin_amdgcn_s_waitcnt(WAIT_VM12);   // drain (it+1)'s loads
        AGG_CONSUME(ar1, br1);
        AGG_ISSUE(ar1, br1);                      // loads for it+3
    }
    // ---- peeled tail: iters NIT-2 (phase0), NIT-1 (phase1) ----
    __builtin_amdgcn_s_waitcnt(WAIT_VM12);
    AGG_CONSUME(ar0, br0);
    __builtin_amdgcn_s_waitcnt(WAIT_VM0);
    AGG_CONSUME(ar1, br1);

#undef AGG_ISSUE
#undef AGG_CONSUME

    // ---- deg reduce + write ----
    if (wave == 0) {
#pragma unroll
        for (int mt = 0; mt < 4; ++mt)
            atomicAdd(&degs[mt * 16 + ln], dacc[mt]);
    }
    __syncthreads();
    if (tid < 64) degP[(size_t)blockIdx.y * NR + m0 + tid] = (float)degs[tid];

    // ---- acc writeback (C/D layout: col=ln, row=q*4+r) ----
    float* const outb = aggP + (size_t)blockIdx.y * NR * DD;
#pragma unroll
    for (int mt = 0; mt < 4; ++mt)
#pragma unroll
        for (int nt = 0; nt < 4; ++nt)
#pragma unroll
            for (int r = 0; r < 4; ++r) {
                const int row = m0 + mt * 16 + q * 4 + r;
                const int col = wave * 64 + nt * 16 + ln;
                outb[(size_t)row * DD + col] = acc[mt][nt][r];
            }
}

// ---------------------------------------------------------------------------
// Kernel 2: out = ((p0+p1)/deg) @ W^T + b    M=16384, N=256, K=256
// ---------------------------------------------------------------------------
__global__ __launch_bounds__(256, 2) void k_lin(const float* __restrict__ aggP,
                                                const float* __restrict__ degP,
                                                const float* __restrict__ W,
                                                const float* __restrict__ bias,
                                                float* __restrict__ out) {
    __shared__ __align__(16) unsigned short As[64 * SA];
    __shared__ __align__(16) unsigned short Bs[256 * SA];
    __shared__ float rdeg[64];
    __shared__ float bsh[256];

    const int tid  = threadIdx.x;
    const int wave = tid >> 6;
    const int lane = tid & 63;
    const int q    = lane >> 4;
    const int ln   = lane & 15;
    const int m0   = blockIdx.x * 64;

    if (tid < 64) {
        float d = 0.f;
#pragma unroll
        for (int s = 0; s < NSPLIT; ++s) d += degP[(size_t)s * NR + m0 + tid];
        rdeg[tid] = 1.0f / d;
    }
    bsh[tid] = bias[tid];

    const int arow = tid >> 4;
    const int acol = (tid & 15) * 4;

    floatx4 acc[4][4] = {};

    for (int it = 0; it < 4; ++it) {
        const int kb = it * 64;
        __syncthreads();

#pragma unroll
        for (int i = 0; i < 4; ++i) {
            const int r = arow + 16 * i;
            const size_t g = (size_t)(m0 + r) * DD + kb + acol;
            float4 p = *(const float4*)(aggP + g);
#pragma unroll
            for (int s = 1; s < NSPLIT; ++s) {
                const float4 ps = *(const float4*)(aggP + (size_t)s * NR * DD + g);
                p.x += ps.x; p.y += ps.y; p.z += ps.z; p.w += ps.w;
            }
            const float sc = rdeg[r];
            ushort4 o;
            o.x = f2bf(p.x * sc);
            o.y = f2bf(p.y * sc);
            o.z = f2bf(p.z * sc);
            o.w = f2bf(p.w * sc);
            *(ushort4*)&As[r * SA + acol] = o;
        }
#pragma unroll
        for (int i = 0; i < 16; ++i) {
            const int r = arow + 16 * i;
            const float4 w4 = *(const float4*)(W + (size_t)r * DD + kb + acol);
            ushort4 o;
            o.x = f2bf(w4.x); o.y = f2bf(w4.y);
            o.z = f2bf(w4.z); o.w = f2bf(w4.w);
            *(ushort4*)&Bs[r * SA + acol] = o;
        }
        __syncthreads();

#pragma unroll
        for (int ks = 0; ks < 2; ++ks) {
            const int kk = ks * 32 + q * 8;
            shortx8 af[4], bf[4];
#pragma unroll
            for (int mt = 0; mt < 4; ++mt)
                af[mt] = *(const shortx8*)&As[(mt * 16 + ln) * SA + kk];
#pragma unroll
            for (int nt = 0; nt < 4; ++nt)
                bf[nt] = *(const shortx8*)&Bs[(wave * 64 + nt * 16 + ln) * SA + kk];
#pragma unroll
            for (int mt = 0; mt < 4; ++mt)
#pragma unroll
                for (int nt = 0; nt < 4; ++nt)
                    acc[mt][nt] = __builtin_amdgcn_mfma_f32_16x16x32_bf16(
                        af[mt], bf[nt], acc[mt][nt], 0, 0, 0);
        }
    }

#pragma unroll
    for (int mt = 0; mt < 4; ++mt)
#pragma unroll
        for (int nt = 0; nt < 4; ++nt)
#pragma unroll
            for (int r = 0; r < 4; ++r) {
                const int row = m0 + mt * 16 + q * 4 + r;
                const int col = wave * 64 + nt * 16 + ln;
                out[(size_t)row * DD + col] = acc[mt][nt][r] + bsh[col];
            }
}

// ---------------------------------------------------------------------------
extern "C" void kernel_launch(void* const* d_in, const int* in_sizes, int n_in,
                              void* d_out, int out_size, void* d_ws, size_t ws_size,
                              hipStream_t stream) {
    const float* x    = (const float*)d_in[0];
    const int*   adj  = (const int*)d_in[1];
    const float* W    = (const float*)d_in[2];
    const float* bias = (const float*)d_in[3];
    float* out = (float*)d_out;

    // ws layout: xT bf16 8 MB | aggP fp32 NSPLIT x 16 MB | degP fp32 NSPLIT x 64 KB
    unsigned short* xT  = (unsigned short*)d_ws;
    float* aggP = (float*)((char*)d_ws + (size_t)8 * 1024 * 1024);
    float* degP = (float*)((char*)d_ws + (size_t)(8 + 16 * NSPLIT) * 1024 * 1024);

    k_xpose<<<dim3(NR / 64, DD / 64), 256, 0, stream>>>(x, xT);
    k_agg<<<dim3(NR / 64, NSPLIT), 256, 0, stream>>>(adj, xT, aggP, degP);
    k_lin<<<dim3(NR / 64), 256, 0, stream>>>(aggP, degP, W, bias, out);
}